// Round 2
// baseline (719.904 us; speedup 1.0000x reference)
//
#include <hip/hip_runtime.h>
#include <hip/hip_bf16.h>

typedef __attribute__((ext_vector_type(8))) __bf16 bf16x8;
typedef __attribute__((ext_vector_type(4))) __bf16 bf16x4;
typedef __attribute__((ext_vector_type(4))) float f32x4;

#define AS1(p) ((__attribute__((address_space(1))) void*)(p))
#define AS3(p) ((__attribute__((address_space(3))) void*)(p))

// ---------------------------------------------------------------- f32 -> bf16
__global__ void f2b_kernel(const float4* __restrict__ in, bf16x4* __restrict__ out, int n4) {
    int idx = blockIdx.x * blockDim.x + threadIdx.x;
    int stride = gridDim.x * blockDim.x;
    for (int i = idx; i < n4; i += stride) {
        float4 v = in[i];
        bf16x4 o;
        o[0] = (__bf16)v.x; o[1] = (__bf16)v.y; o[2] = (__bf16)v.z; o[3] = (__bf16)v.w;
        out[i] = o;
    }
}

// ---------------------------------------------------------------- GEMM C = A @ B^T
__global__ __launch_bounds__(256)
void gemm_bt(const __bf16* __restrict__ A, const __bf16* __restrict__ Bw,
             const float* __restrict__ bias, float* __restrict__ Cf,
             __bf16* __restrict__ Cb, int M, int N, int K)
{
    __shared__ __bf16 As[128 * 32];
    __shared__ __bf16 Bs[128 * 32];
    const int tid = threadIdx.x;
    const int l = tid & 63, w = tid >> 6;
    const int m0 = blockIdx.y * 128, n0 = blockIdx.x * 128;
    const int wr = (w >> 1) * 64, wc = (w & 1) * 64;
    const int fr = l & 15, koff = (l >> 4) * 8;

    f32x4 acc[4][4] = {};

    const int c0 = tid, c1 = tid + 256;
    const __bf16* Ab = A + m0 * K;
    const __bf16* Bb = Bw + n0 * K;
    const int ga0 = (c0 >> 2) * K + (c0 & 3) * 8;
    const int ga1 = (c1 >> 2) * K + (c1 & 3) * 8;

    for (int k0 = 0; k0 < K; k0 += 32) {
        __builtin_amdgcn_global_load_lds(AS1(Ab + ga0 + k0), AS3(As + c0 * 8), 16, 0, 0);
        __builtin_amdgcn_global_load_lds(AS1(Ab + ga1 + k0), AS3(As + c1 * 8), 16, 0, 0);
        __builtin_amdgcn_global_load_lds(AS1(Bb + ga0 + k0), AS3(Bs + c0 * 8), 16, 0, 0);
        __builtin_amdgcn_global_load_lds(AS1(Bb + ga1 + k0), AS3(Bs + c1 * 8), 16, 0, 0);
        __syncthreads();

        bf16x8 af[4], bfv[4];
        #pragma unroll
        for (int m = 0; m < 4; ++m)
            af[m] = *(const bf16x8*)&As[(wr + m * 16 + fr) * 32 + koff];
        #pragma unroll
        for (int n = 0; n < 4; ++n)
            bfv[n] = *(const bf16x8*)&Bs[(wc + n * 16 + fr) * 32 + koff];
        #pragma unroll
        for (int m = 0; m < 4; ++m)
            #pragma unroll
            for (int n = 0; n < 4; ++n)
                acc[m][n] = __builtin_amdgcn_mfma_f32_16x16x32_bf16(af[m], bfv[n], acc[m][n], 0, 0, 0);
        __syncthreads();
    }

    #pragma unroll
    for (int m = 0; m < 4; ++m) {
        #pragma unroll
        for (int n = 0; n < 4; ++n) {
            const int row = m0 + wr + m * 16 + (l >> 4) * 4;
            const int col = n0 + wc + n * 16 + fr;
            const float bv = bias ? bias[col] : 0.0f;
            #pragma unroll
            for (int r = 0; r < 4; ++r) {
                float v = acc[m][n][r] + bv;
                if (Cf) Cf[(row + r) * N + col] = v;
                else    Cb[(row + r) * N + col] = (__bf16)v;
            }
        }
    }
}

// ---------------------------------------------------------------- RMSNorm on q,k (in place)
__global__ __launch_bounds__(256)
void rmsnorm_kernel(__bf16* __restrict__ qkv, const float* __restrict__ qw,
                    const float* __restrict__ kw)
{
    const int row = blockIdx.x;
    const int t = threadIdx.x;
    const int g = t >> 3, j = t & 7;
    const int part = g >> 4, head = g & 15;
    const int base = row * 3072 + part * 1024 + head * 64 + j * 8;
    bf16x8 v = *(const bf16x8*)&qkv[base];
    float s = 0.0f;
    #pragma unroll
    for (int i = 0; i < 8; ++i) { float f = (float)v[i]; s += f * f; }
    s += __shfl_xor(s, 1); s += __shfl_xor(s, 2); s += __shfl_xor(s, 4);
    float r = rsqrtf(s * (1.0f / 64.0f) + 1e-6f);
    if (part == 0) r *= 0.125f;
    const float* wp = (part == 0) ? qw : kw;
    bf16x8 o;
    #pragma unroll
    for (int i = 0; i < 8; ++i) o[i] = (__bf16)((float)v[i] * r * wp[j * 8 + i]);
    *(bf16x8*)&qkv[base] = o;
}

// ---------------------------------------------------------------- V transpose: vt[b][h][d][n]
__global__ __launch_bounds__(256)
void vtrans_kernel(const __bf16* __restrict__ qkv, __bf16* __restrict__ vt)
{
    __shared__ __bf16 T[64][72];   // T[n_local][d_local], pad to keep 16B-aligned rows
    const int b = blockIdx.z, h = blockIdx.y, nb = blockIdx.x;
    const int t = threadIdx.x;
    {
        const int nl = t >> 2, q4 = t & 3;
        const __bf16* src = qkv + (size_t)(b * 1024 + nb * 64 + nl) * 3072 + 2048 + h * 64 + q4 * 16;
        bf16x8 v0 = *(const bf16x8*)src;
        bf16x8 v1 = *(const bf16x8*)(src + 8);
        *(bf16x8*)&T[nl][q4 * 16] = v0;
        *(bf16x8*)&T[nl][q4 * 16 + 8] = v1;
    }
    __syncthreads();
    {
        const int dl = t >> 2, nq = t & 3;
        bf16x8 o0, o1;
        #pragma unroll
        for (int i = 0; i < 8; ++i) { o0[i] = T[nq * 16 + i][dl]; o1[i] = T[nq * 16 + 8 + i][dl]; }
        __bf16* dst = vt + ((size_t)((b * 16 + h) * 64 + dl)) * 1024 + nb * 64 + nq * 16;
        *(bf16x8*)dst = o0;
        *(bf16x8*)(dst + 8) = o1;
    }
}

// ---------------------------------------------------------------- flash attention (barrier-free)
// grid (16 qblocks, 16 heads, 16 batch), 256 thr, 4 independent waves x 16 q-rows.
// Swapped QK^T: lane (fr,fk) holds S[key=n*16+fk*4+r][q=fr]. P via per-wave swizzled LDS.
__global__ __launch_bounds__(256)
void attn_kernel(const __bf16* __restrict__ qkv, const __bf16* __restrict__ vt,
                 __bf16* __restrict__ ao)
{
    __shared__ __bf16 Pl[4][16 * 64];    // per-wave Pt[q][key], XOR-swizzled rows
    const int tid = threadIdx.x, l = tid & 63, w = tid >> 6;
    const int b = blockIdx.z, h = blockIdx.y, qb = blockIdx.x;
    const int fr = l & 15, fk = l >> 4;
    const int sw = (fr & 7) << 4;        // XOR swizzle within 128B row

    const int qrow0 = b * 1024 + qb * 64 + w * 16;
    bf16x8 qf[2];
    #pragma unroll
    for (int dc = 0; dc < 2; ++dc)
        qf[dc] = *(const bf16x8*)&qkv[(size_t)(qrow0 + fr) * 3072 + h * 64 + dc * 32 + fk * 8];

    float m_r = -1e30f, ls = 0.0f;
    f32x4 oacc[4] = {};

    const __bf16* Kb = qkv + (size_t)b * 1024 * 3072 + 1024 + h * 64;
    const __bf16* Vb = vt + (size_t)(b * 16 + h) * 64 * 1024;
    char* Pw = (char*)&Pl[w][0];

    for (int kt = 0; kt < 16; ++kt) {
        // S^T = K @ Q^T (scale folded into q)
        f32x4 sacc[4] = {};
        #pragma unroll
        for (int n = 0; n < 4; ++n)
            #pragma unroll
            for (int dc = 0; dc < 2; ++dc) {
                bf16x8 kf = *(const bf16x8*)&Kb[(size_t)(kt * 64 + n * 16 + fr) * 3072 + dc * 32 + fk * 8];
                sacc[n] = __builtin_amdgcn_mfma_f32_16x16x32_bf16(kf, qf[dc], sacc[n], 0, 0, 0);
            }

        // online softmax: all 16 lane values share q = fr
        float tm = -1e30f;
        #pragma unroll
        for (int n = 0; n < 4; ++n)
            #pragma unroll
            for (int r = 0; r < 4; ++r)
                tm = fmaxf(tm, sacc[n][r]);
        tm = fmaxf(tm, __shfl_xor(tm, 16));
        tm = fmaxf(tm, __shfl_xor(tm, 32));
        const float mnew = fmaxf(m_r, tm);
        const float resc = __expf(m_r - mnew);
        m_r = mnew;

        float psum = 0.0f;
        #pragma unroll
        for (int n = 0; n < 4; ++n) {
            bf16x4 pk;
            #pragma unroll
            for (int r = 0; r < 4; ++r) {
                float p = __expf(sacc[n][r] - mnew);
                psum += p;
                pk[r] = (__bf16)p;
            }
            *(bf16x4*)(Pw + ((fr * 128 + n * 32 + fk * 8) ^ sw)) = pk;
        }
        psum += __shfl_xor(psum, 16);
        psum += __shfl_xor(psum, 32);
        ls = ls * resc + psum;

        // rescale O (rows q = fk*4+r -> broadcast resc from lane fr'=fk*4+r, same fk group)
        float rb[4];
        #pragma unroll
        for (int r = 0; r < 4; ++r) rb[r] = __shfl(resc, (l & 48) + fk * 4 + r);
        #pragma unroll
        for (int nd = 0; nd < 4; ++nd)
            #pragma unroll
            for (int r = 0; r < 4; ++r) oacc[nd][r] *= rb[r];

        // O += P @ V  (A = Pt[q][key] from LDS, B = Vt[d][key] from global)
        #pragma unroll
        for (int nd = 0; nd < 4; ++nd)
            #pragma unroll
            for (int kc = 0; kc < 2; ++kc) {
                bf16x8 pf = *(const bf16x8*)(Pw + ((fr * 128 + kc * 64 + fk * 16) ^ sw));
                bf16x8 vf = *(const bf16x8*)&Vb[(size_t)(nd * 16 + fr) * 1024 + kt * 64 + kc * 32 + fk * 8];
                oacc[nd] = __builtin_amdgcn_mfma_f32_16x16x32_bf16(pf, vf, oacc[nd], 0, 0, 0);
            }
    }

    float lsb[4];
    #pragma unroll
    for (int r = 0; r < 4; ++r) lsb[r] = __shfl(ls, (l & 48) + fk * 4 + r);
    #pragma unroll
    for (int nd = 0; nd < 4; ++nd)
        #pragma unroll
        for (int r = 0; r < 4; ++r)
            ao[(size_t)(qrow0 + fk * 4 + r) * 1024 + h * 64 + nd * 16 + fr] =
                (__bf16)(oacc[nd][r] / lsb[r]);
}

// ---------------------------------------------------------------- launch
extern "C" void kernel_launch(void* const* d_in, const int* in_sizes, int n_in,
                              void* d_out, int out_size, void* d_ws, size_t ws_size,
                              hipStream_t stream)
{
    const float* x      = (const float*)d_in[0];
    const float* qkv_w  = (const float*)d_in[1];
    const float* proj_w = (const float*)d_in[2];
    const float* proj_b = (const float*)d_in[3];
    const float* qnw    = (const float*)d_in[4];
    const float* knw    = (const float*)d_in[5];

    char* ws = (char*)d_ws;
    __bf16* xb    = (__bf16*)(ws);                                 // 32 MB (reused as vt later)
    __bf16* wqkv  = (__bf16*)(ws + 33554432);                      // 6 MB
    __bf16* wproj = (__bf16*)(ws + 33554432 + 6291456);            // 2 MB
    __bf16* qkv   = (__bf16*)(ws + 41943040);                      // 96 MB
    __bf16* ao    = (__bf16*)(ws + 41943040 + 100663296);          // 32 MB
    __bf16* vt    = xb;                                            // xb dead after QKV GEMM

    f2b_kernel<<<2048, 256, 0, stream>>>((const float4*)x,      (bf16x4*)xb,    16777216 / 4);
    f2b_kernel<<<2048, 256, 0, stream>>>((const float4*)qkv_w,  (bf16x4*)wqkv,  3145728 / 4);
    f2b_kernel<<<1024, 256, 0, stream>>>((const float4*)proj_w, (bf16x4*)wproj, 1048576 / 4);

    gemm_bt<<<dim3(24, 128), 256, 0, stream>>>(xb, wqkv, nullptr, nullptr, qkv, 16384, 3072, 1024);
    rmsnorm_kernel<<<16384, 256, 0, stream>>>(qkv, qnw, knw);
    vtrans_kernel<<<dim3(16, 16, 16), 256, 0, stream>>>(qkv, vt);
    attn_kernel<<<dim3(16, 16, 16), 256, 0, stream>>>(qkv, vt, ao);
    gemm_bt<<<dim3(8, 128), 256, 0, stream>>>(ao, wproj, proj_b, (float*)d_out, nullptr, 16384, 1024, 1024);
}

// Round 3
// 386.671 us; speedup vs baseline: 1.8618x; 1.8618x over previous
//
#include <hip/hip_runtime.h>
#include <hip/hip_bf16.h>

typedef __attribute__((ext_vector_type(8))) __bf16 bf16x8;
typedef __attribute__((ext_vector_type(4))) __bf16 bf16x4;
typedef __attribute__((ext_vector_type(4))) float f32x4;

#define AS1(p) ((__attribute__((address_space(1))) void*)(p))
#define AS3(p) ((__attribute__((address_space(3))) void*)(p))

// ---------------------------------------------------------------- f32 -> bf16
__global__ void f2b_kernel(const float4* __restrict__ in, bf16x4* __restrict__ out, int n4) {
    int idx = blockIdx.x * blockDim.x + threadIdx.x;
    int stride = gridDim.x * blockDim.x;
    for (int i = idx; i < n4; i += stride) {
        float4 v = in[i];
        bf16x4 o;
        o[0] = (__bf16)v.x; o[1] = (__bf16)v.y; o[2] = (__bf16)v.z; o[3] = (__bf16)v.w;
        out[i] = o;
    }
}

// ---------------------------------------------------------------- GEMM C = A @ B^T
__global__ __launch_bounds__(256)
void gemm_bt(const __bf16* __restrict__ A, const __bf16* __restrict__ Bw,
             const float* __restrict__ bias, float* __restrict__ Cf,
             __bf16* __restrict__ Cb, int M, int N, int K)
{
    __shared__ __bf16 As[128 * 32];
    __shared__ __bf16 Bs[128 * 32];
    const int tid = threadIdx.x;
    const int l = tid & 63, w = tid >> 6;
    const int m0 = blockIdx.y * 128, n0 = blockIdx.x * 128;
    const int wr = (w >> 1) * 64, wc = (w & 1) * 64;
    const int fr = l & 15, koff = (l >> 4) * 8;

    f32x4 acc[4][4] = {};

    const int c0 = tid, c1 = tid + 256;
    const __bf16* Ab = A + m0 * K;
    const __bf16* Bb = Bw + n0 * K;
    const int ga0 = (c0 >> 2) * K + (c0 & 3) * 8;
    const int ga1 = (c1 >> 2) * K + (c1 & 3) * 8;

    for (int k0 = 0; k0 < K; k0 += 32) {
        __builtin_amdgcn_global_load_lds(AS1(Ab + ga0 + k0), AS3(As + c0 * 8), 16, 0, 0);
        __builtin_amdgcn_global_load_lds(AS1(Ab + ga1 + k0), AS3(As + c1 * 8), 16, 0, 0);
        __builtin_amdgcn_global_load_lds(AS1(Bb + ga0 + k0), AS3(Bs + c0 * 8), 16, 0, 0);
        __builtin_amdgcn_global_load_lds(AS1(Bb + ga1 + k0), AS3(Bs + c1 * 8), 16, 0, 0);
        __syncthreads();

        bf16x8 af[4], bfv[4];
        #pragma unroll
        for (int m = 0; m < 4; ++m)
            af[m] = *(const bf16x8*)&As[(wr + m * 16 + fr) * 32 + koff];
        #pragma unroll
        for (int n = 0; n < 4; ++n)
            bfv[n] = *(const bf16x8*)&Bs[(wc + n * 16 + fr) * 32 + koff];
        #pragma unroll
        for (int m = 0; m < 4; ++m)
            #pragma unroll
            for (int n = 0; n < 4; ++n)
                acc[m][n] = __builtin_amdgcn_mfma_f32_16x16x32_bf16(af[m], bfv[n], acc[m][n], 0, 0, 0);
        __syncthreads();
    }

    #pragma unroll
    for (int m = 0; m < 4; ++m) {
        #pragma unroll
        for (int n = 0; n < 4; ++n) {
            const int row = m0 + wr + m * 16 + (l >> 4) * 4;
            const int col = n0 + wc + n * 16 + fr;
            const float bv = bias ? bias[col] : 0.0f;
            #pragma unroll
            for (int r = 0; r < 4; ++r) {
                float v = acc[m][n][r] + bv;
                if (Cf) Cf[(row + r) * N + col] = v;
                else    Cb[(row + r) * N + col] = (__bf16)v;
            }
        }
    }
}

// ---------------------------------------------------------------- RMSNorm on q,k (in place)
__global__ __launch_bounds__(256)
void rmsnorm_kernel(__bf16* __restrict__ qkv, const float* __restrict__ qw,
                    const float* __restrict__ kw)
{
    const int row = blockIdx.x;
    const int t = threadIdx.x;
    const int g = t >> 3, j = t & 7;
    const int part = g >> 4, head = g & 15;
    const int base = row * 3072 + part * 1024 + head * 64 + j * 8;
    bf16x8 v = *(const bf16x8*)&qkv[base];
    float s = 0.0f;
    #pragma unroll
    for (int i = 0; i < 8; ++i) { float f = (float)v[i]; s += f * f; }
    s += __shfl_xor(s, 1); s += __shfl_xor(s, 2); s += __shfl_xor(s, 4);
    float r = rsqrtf(s * (1.0f / 64.0f) + 1e-6f);
    if (part == 0) r *= 0.125f;
    const float* wp = (part == 0) ? qw : kw;
    bf16x8 o;
    #pragma unroll
    for (int i = 0; i < 8; ++i) o[i] = (__bf16)((float)v[i] * r * wp[j * 8 + i]);
    *(bf16x8*)&qkv[base] = o;
}

// ---------------------------------------------------------------- V transpose: vt[b][h][d][n]
__global__ __launch_bounds__(256)
void vtrans_kernel(const __bf16* __restrict__ qkv, __bf16* __restrict__ vt)
{
    __shared__ __bf16 T[64][72];
    const int b = blockIdx.z, h = blockIdx.y, nb = blockIdx.x;
    const int t = threadIdx.x;
    {
        const int nl = t >> 2, q4 = t & 3;
        const __bf16* src = qkv + (size_t)(b * 1024 + nb * 64 + nl) * 3072 + 2048 + h * 64 + q4 * 16;
        bf16x8 v0 = *(const bf16x8*)src;
        bf16x8 v1 = *(const bf16x8*)(src + 8);
        *(bf16x8*)&T[nl][q4 * 16] = v0;
        *(bf16x8*)&T[nl][q4 * 16 + 8] = v1;
    }
    __syncthreads();
    {
        const int dl = t >> 2, nq = t & 3;
        bf16x8 o0, o1;
        #pragma unroll
        for (int i = 0; i < 8; ++i) { o0[i] = T[nq * 16 + i][dl]; o1[i] = T[nq * 16 + 8 + i][dl]; }
        __bf16* dst = vt + ((size_t)((b * 16 + h) * 64 + dl)) * 1024 + nb * 64 + nq * 16;
        *(bf16x8*)dst = o0;
        *(bf16x8*)(dst + 8) = o1;
    }
}

// ---------------------------------------------------------------- flash attention v3
// grid 1024 (XCD-chunk-swizzled -> (qb,h,b)), 256 thr = 4 waves x 64 q-rows.
// K,V^T tiles double-buffered in LDS via pre-swizzled global_load_lds; frags
// reused across 4 q-tiles per wave; per-wave P round-trip in swizzled LDS.
__global__ __launch_bounds__(256, 2)
void attn_kernel(const __bf16* __restrict__ qkv, const __bf16* __restrict__ vt,
                 __bf16* __restrict__ ao)
{
    __shared__ __bf16 Ks[2][64 * 64];
    __shared__ __bf16 Vs[2][64 * 64];
    __shared__ __bf16 Pl[4][16 * 64];
    const int tid = threadIdx.x, l = tid & 63, w = tid >> 6;
    const int fr = l & 15, fk = l >> 4;
    const int sw = (fr & 7) << 4;

    // XCD-chunked: 1024 blocks / 8 XCDs; the 4 q-blocks of a head stay together
    const int bi = blockIdx.x;
    const int L = (bi & 7) * 128 + (bi >> 3);
    const int qb = L & 3, h = (L >> 2) & 15, b = L >> 6;

    const __bf16* Kg = qkv + (size_t)b * 1024 * 3072 + 1024 + h * 64;
    const __bf16* Vg = vt + (size_t)((b * 16 + h) * 64) * 1024;
    const int srow = tid >> 3, scp = tid & 7;

#define STAGE(KT, BUF) do {                                                               \
    _Pragma("unroll")                                                                     \
    for (int i_ = 0; i_ < 2; ++i_) {                                                      \
        const int row_ = i_ * 32 + srow;                                                  \
        const int c_ = scp ^ (row_ & 7);                                                  \
        __builtin_amdgcn_global_load_lds(AS1(Kg + (size_t)((KT) * 64 + row_) * 3072 + c_ * 8), \
                                         AS3(&Ks[BUF][i_ * 2048 + tid * 8]), 16, 0, 0);   \
        __builtin_amdgcn_global_load_lds(AS1(Vg + (size_t)row_ * 1024 + (KT) * 64 + c_ * 8),   \
                                         AS3(&Vs[BUF][i_ * 2048 + tid * 8]), 16, 0, 0);   \
    } } while (0)

    STAGE(0, 0);

    const int qrow0 = b * 1024 + qb * 256 + w * 64;
    bf16x8 qf[4][2];
    #pragma unroll
    for (int qi = 0; qi < 4; ++qi)
        #pragma unroll
        for (int dc = 0; dc < 2; ++dc)
            qf[qi][dc] = *(const bf16x8*)&qkv[(size_t)(qrow0 + qi * 16 + fr) * 3072
                                              + h * 64 + dc * 32 + fk * 8];

    f32x4 oacc[4][4] = {};
    float m_r[4], ls[4];
    #pragma unroll
    for (int qi = 0; qi < 4; ++qi) { m_r[qi] = -1e30f; ls[qi] = 0.0f; }

    char* Pw = (char*)&Pl[w][0];
    __syncthreads();

    for (int kt = 0; kt < 16; ++kt) {
        const int cur = kt & 1;
        if (kt < 15) STAGE(kt + 1, cur ^ 1);

        bf16x8 kf[4][2], vf[4][2];
        #pragma unroll
        for (int n = 0; n < 4; ++n)
            #pragma unroll
            for (int dc = 0; dc < 2; ++dc)
                kf[n][dc] = *(const bf16x8*)&Ks[cur][(n * 16 + fr) * 64
                                                     + (((dc * 4 + fk) ^ (fr & 7)) * 8)];
        #pragma unroll
        for (int nd = 0; nd < 4; ++nd)
            #pragma unroll
            for (int kc = 0; kc < 2; ++kc)
                vf[nd][kc] = *(const bf16x8*)&Vs[cur][(nd * 16 + fr) * 64
                                                      + (((kc * 4 + fk) ^ (fr & 7)) * 8)];

        #pragma unroll
        for (int qi = 0; qi < 4; ++qi) {
            // S^T = K @ Q^T (scale folded into q); lane holds S[key=n*16+fk*4+r][q=fr]
            f32x4 sacc[4] = {};
            #pragma unroll
            for (int n = 0; n < 4; ++n)
                #pragma unroll
                for (int dc = 0; dc < 2; ++dc)
                    sacc[n] = __builtin_amdgcn_mfma_f32_16x16x32_bf16(kf[n][dc], qf[qi][dc],
                                                                      sacc[n], 0, 0, 0);

            float tm = -1e30f;
            #pragma unroll
            for (int n = 0; n < 4; ++n)
                #pragma unroll
                for (int r = 0; r < 4; ++r)
                    tm = fmaxf(tm, sacc[n][r]);
            tm = fmaxf(tm, __shfl_xor(tm, 16));
            tm = fmaxf(tm, __shfl_xor(tm, 32));
            const float mnew = fmaxf(m_r[qi], tm);
            const float resc = __expf(m_r[qi] - mnew);
            m_r[qi] = mnew;

            float psum = 0.0f;
            #pragma unroll
            for (int n = 0; n < 4; ++n) {
                bf16x4 pk;
                #pragma unroll
                for (int r = 0; r < 4; ++r) {
                    float p = __expf(sacc[n][r] - mnew);
                    psum += p;
                    pk[r] = (__bf16)p;
                }
                *(bf16x4*)(Pw + ((fr * 128 + n * 32 + fk * 8) ^ sw)) = pk;
            }
            psum += __shfl_xor(psum, 16);
            psum += __shfl_xor(psum, 32);
            ls[qi] = ls[qi] * resc + psum;

            float rb[4];
            #pragma unroll
            for (int r = 0; r < 4; ++r) rb[r] = __shfl(resc, (l & 48) + fk * 4 + r);
            #pragma unroll
            for (int nd = 0; nd < 4; ++nd)
                #pragma unroll
                for (int r = 0; r < 4; ++r) oacc[qi][nd][r] *= rb[r];

            bf16x8 pf[2];
            #pragma unroll
            for (int kc = 0; kc < 2; ++kc)
                pf[kc] = *(const bf16x8*)(Pw + ((fr * 128 + kc * 64 + fk * 16) ^ sw));
            #pragma unroll
            for (int nd = 0; nd < 4; ++nd)
                #pragma unroll
                for (int kc = 0; kc < 2; ++kc)
                    oacc[qi][nd] = __builtin_amdgcn_mfma_f32_16x16x32_bf16(pf[kc], vf[nd][kc],
                                                                           oacc[qi][nd], 0, 0, 0);
        }
        __syncthreads();
    }

    #pragma unroll
    for (int qi = 0; qi < 4; ++qi) {
        float lsb[4];
        #pragma unroll
        for (int r = 0; r < 4; ++r) lsb[r] = __shfl(ls[qi], (l & 48) + fk * 4 + r);
        #pragma unroll
        for (int nd = 0; nd < 4; ++nd)
            #pragma unroll
            for (int r = 0; r < 4; ++r)
                ao[(size_t)(qrow0 + qi * 16 + fk * 4 + r) * 1024 + h * 64 + nd * 16 + fr] =
                    (__bf16)(oacc[qi][nd][r] / lsb[r]);
    }
#undef STAGE
}

// ---------------------------------------------------------------- launch
extern "C" void kernel_launch(void* const* d_in, const int* in_sizes, int n_in,
                              void* d_out, int out_size, void* d_ws, size_t ws_size,
                              hipStream_t stream)
{
    const float* x      = (const float*)d_in[0];
    const float* qkv_w  = (const float*)d_in[1];
    const float* proj_w = (const float*)d_in[2];
    const float* proj_b = (const float*)d_in[3];
    const float* qnw    = (const float*)d_in[4];
    const float* knw    = (const float*)d_in[5];

    char* ws = (char*)d_ws;
    __bf16* xb    = (__bf16*)(ws);                                 // 32 MB (reused as vt later)
    __bf16* wqkv  = (__bf16*)(ws + 33554432);                      // 6 MB
    __bf16* wproj = (__bf16*)(ws + 33554432 + 6291456);            // 2 MB
    __bf16* qkv   = (__bf16*)(ws + 41943040);                      // 96 MB
    __bf16* ao    = (__bf16*)(ws + 41943040 + 100663296);          // 32 MB
    __bf16* vt    = xb;                                            // xb dead after QKV GEMM

    f2b_kernel<<<2048, 256, 0, stream>>>((const float4*)x,      (bf16x4*)xb,    16777216 / 4);
    f2b_kernel<<<2048, 256, 0, stream>>>((const float4*)qkv_w,  (bf16x4*)wqkv,  3145728 / 4);
    f2b_kernel<<<1024, 256, 0, stream>>>((const float4*)proj_w, (bf16x4*)wproj, 1048576 / 4);

    gemm_bt<<<dim3(24, 128), 256, 0, stream>>>(xb, wqkv, nullptr, nullptr, qkv, 16384, 3072, 1024);
    rmsnorm_kernel<<<16384, 256, 0, stream>>>(qkv, qnw, knw);
    vtrans_kernel<<<dim3(16, 16, 16), 256, 0, stream>>>(qkv, vt);
    attn_kernel<<<1024, 256, 0, stream>>>(qkv, vt, ao);
    gemm_bt<<<dim3(8, 128), 256, 0, stream>>>(ao, wproj, proj_b, (float*)d_out, nullptr, 16384, 1024, 1024);
}

// Round 4
// 305.953 us; speedup vs baseline: 2.3530x; 1.2638x over previous
//
#include <hip/hip_runtime.h>
#include <hip/hip_bf16.h>

typedef __attribute__((ext_vector_type(8))) __bf16 bf16x8;
typedef __attribute__((ext_vector_type(4))) __bf16 bf16x4;
typedef __attribute__((ext_vector_type(4))) float f32x4;

#define AS1(p) ((__attribute__((address_space(1))) void*)(p))
#define AS3(p) ((__attribute__((address_space(3))) void*)(p))

// ---------------------------------------------------------------- f32 -> bf16
__global__ void f2b_kernel(const float4* __restrict__ in, bf16x4* __restrict__ out, int n4) {
    int idx = blockIdx.x * blockDim.x + threadIdx.x;
    int stride = gridDim.x * blockDim.x;
    for (int i = idx; i < n4; i += stride) {
        float4 v = in[i];
        bf16x4 o;
        o[0] = (__bf16)v.x; o[1] = (__bf16)v.y; o[2] = (__bf16)v.z; o[3] = (__bf16)v.w;
        out[i] = o;
    }
}

// ---------------------------------------------------------------- 256x256 pipelined GEMM
// C = A @ B^T. 512 thr = 8 waves (2M x 4N), per-wave 128x64 output, acc[8][4].
// K in 32-wide slots; 4-slot LDS ring staged 3 ahead (counted vmcnt, 1 barrier/slot).
// MODE 0: qkv out bf16 + fused per-head RMSNorm (q scaled by Dh^-0.5).
// MODE 1: f32 out + bias.
template<int MODE>
__global__ __launch_bounds__(512, 2)
void gemm256(const __bf16* __restrict__ A, const __bf16* __restrict__ Bw,
             const float* __restrict__ bias, const float* __restrict__ qw,
             const float* __restrict__ kw, float* __restrict__ Cf,
             __bf16* __restrict__ Cb, int M, int N, int K, int nbn)
{
    __shared__ __bf16 Asl[4][256 * 32];
    __shared__ __bf16 Bsl[4][256 * 32];
    const int tid = threadIdx.x, l = tid & 63, w = tid >> 6;
    const int fr = l & 15, fk = l >> 4;

    // XCD-chunked bijective swizzle (gridDim.x divisible by 8)
    const int cpx = gridDim.x >> 3;
    const int wg = (blockIdx.x & 7) * cpx + (blockIdx.x >> 3);
    const int bm = wg / nbn, bn = wg % nbn;

    const __bf16* Ag = A + (size_t)bm * 256 * K;
    const __bf16* Bg = Bw + (size_t)bn * 256 * K;

    // staging: thread -> (row = tid>>2, chunk = tid&3); source pre-swizzled chunk^row&3
    const int arow = tid >> 2;
    const int uch = (tid & 3) ^ (arow & 3);
    const size_t ga = (size_t)arow * K + uch * 8;
    const size_t ga2 = ga + (size_t)128 * K;

    // frag read offsets (bytes), swizzled chunk = fk ^ (row&3) = fk ^ (fr&3)
    const int axc = (fk ^ (fr & 3)) * 16;
    int aoff[8], boff[4];
    #pragma unroll
    for (int m = 0; m < 8; ++m)
        aoff[m] = ((w >> 2) * 128 + m * 16 + fr) * 64 + axc;
    #pragma unroll
    for (int n = 0; n < 4; ++n)
        boff[n] = ((w & 3) * 64 + n * 16 + fr) * 64 + axc;

    f32x4 acc[8][4] = {};

#define STAGE256(S) do {                                                                    \
    const int sb_ = (S) & 3;                                                                \
    __builtin_amdgcn_global_load_lds(AS1(Ag + (size_t)(S) * 32 + ga),                       \
        AS3((char*)&Asl[sb_][0] + tid * 16), 16, 0, 0);                                     \
    __builtin_amdgcn_global_load_lds(AS1(Ag + (size_t)(S) * 32 + ga2),                      \
        AS3((char*)&Asl[sb_][0] + tid * 16 + 8192), 16, 0, 0);                              \
    __builtin_amdgcn_global_load_lds(AS1(Bg + (size_t)(S) * 32 + ga),                       \
        AS3((char*)&Bsl[sb_][0] + tid * 16), 16, 0, 0);                                     \
    __builtin_amdgcn_global_load_lds(AS1(Bg + (size_t)(S) * 32 + ga2),                      \
        AS3((char*)&Bsl[sb_][0] + tid * 16 + 8192), 16, 0, 0);                              \
} while (0)

#define PHASE256(S, VMSTR, DOSTAGE) do {                                                    \
    asm volatile("s_waitcnt vmcnt(" VMSTR ")" ::: "memory");                                \
    __builtin_amdgcn_s_barrier();                                                           \
    __builtin_amdgcn_sched_barrier(0);                                                      \
    const int pb_ = (S) & 3;                                                                \
    bf16x8 af[8], bfv[4];                                                                   \
    _Pragma("unroll")                                                                       \
    for (int m = 0; m < 8; ++m)                                                             \
        af[m] = *(const bf16x8*)((const char*)&Asl[pb_][0] + aoff[m]);                      \
    _Pragma("unroll")                                                                       \
    for (int n = 0; n < 4; ++n)                                                             \
        bfv[n] = *(const bf16x8*)((const char*)&Bsl[pb_][0] + boff[n]);                     \
    if (DOSTAGE) STAGE256((S) + 3);                                                         \
    __builtin_amdgcn_s_setprio(1);                                                          \
    _Pragma("unroll")                                                                       \
    for (int m = 0; m < 8; ++m)                                                             \
        _Pragma("unroll")                                                                   \
        for (int n = 0; n < 4; ++n)                                                         \
            acc[m][n] = __builtin_amdgcn_mfma_f32_16x16x32_bf16(af[m], bfv[n], acc[m][n], 0, 0, 0); \
    __builtin_amdgcn_s_setprio(0);                                                          \
} while (0)

    const int S = K >> 5;
    STAGE256(0); STAGE256(1); STAGE256(2);
    for (int s = 0; s < S - 2; ++s)
        PHASE256(s, "8", (s + 3 < S));
    PHASE256(S - 2, "4", false);
    PHASE256(S - 1, "0", false);
#undef PHASE256
#undef STAGE256

    // ---------------- epilogue: C/D layout col = fr, row = fk*4 + r
    const int rb0 = bm * 256 + (w >> 2) * 128 + fk * 4;
    const int cb0 = bn * 256 + (w & 3) * 64;

    if (MODE == 1) {
        #pragma unroll
        for (int m = 0; m < 8; ++m)
            #pragma unroll
            for (int n = 0; n < 4; ++n) {
                const int col = cb0 + n * 16 + fr;
                const float bv = bias[col];
                #pragma unroll
                for (int r = 0; r < 4; ++r)
                    Cf[(size_t)(rb0 + m * 16 + r) * N + col] = acc[m][n][r] + bv;
            }
    } else {
        const int sect = bn >> 2;          // 0=q, 1=k, 2=v (nbn=12)
        float wn[4] = {1.f, 1.f, 1.f, 1.f};
        if (sect < 2) {
            const float* wp = (sect == 0) ? qw : kw;
            #pragma unroll
            for (int n = 0; n < 4; ++n) wn[n] = wp[n * 16 + fr];
        }
        #pragma unroll
        for (int m = 0; m < 8; ++m) {
            if (sect < 2) {
                float sc[4];
                #pragma unroll
                for (int r = 0; r < 4; ++r) {
                    float ps = 0.f;
                    #pragma unroll
                    for (int n = 0; n < 4; ++n) ps += acc[m][n][r] * acc[m][n][r];
                    ps += __shfl_xor(ps, 1); ps += __shfl_xor(ps, 2);
                    ps += __shfl_xor(ps, 4); ps += __shfl_xor(ps, 8);
                    sc[r] = rsqrtf(ps * (1.0f / 64.0f) + 1e-6f);
                    if (sect == 0) sc[r] *= 0.125f;
                }
                #pragma unroll
                for (int n = 0; n < 4; ++n)
                    #pragma unroll
                    for (int r = 0; r < 4; ++r)
                        Cb[(size_t)(rb0 + m * 16 + r) * N + cb0 + n * 16 + fr] =
                            (__bf16)(acc[m][n][r] * sc[r] * wn[n]);
            } else {
                #pragma unroll
                for (int n = 0; n < 4; ++n)
                    #pragma unroll
                    for (int r = 0; r < 4; ++r)
                        Cb[(size_t)(rb0 + m * 16 + r) * N + cb0 + n * 16 + fr] =
                            (__bf16)acc[m][n][r];
            }
        }
    }
}

// ---------------------------------------------------------------- V transpose: vt[b][h][d][n]
__global__ __launch_bounds__(256)
void vtrans_kernel(const __bf16* __restrict__ qkv, __bf16* __restrict__ vt)
{
    __shared__ __bf16 T[64][72];
    const int b = blockIdx.z, h = blockIdx.y, nb = blockIdx.x;
    const int t = threadIdx.x;
    {
        const int nl = t >> 2, q4 = t & 3;
        const __bf16* src = qkv + (size_t)(b * 1024 + nb * 64 + nl) * 3072 + 2048 + h * 64 + q4 * 16;
        bf16x8 v0 = *(const bf16x8*)src;
        bf16x8 v1 = *(const bf16x8*)(src + 8);
        *(bf16x8*)&T[nl][q4 * 16] = v0;
        *(bf16x8*)&T[nl][q4 * 16 + 8] = v1;
    }
    __syncthreads();
    {
        const int dl = t >> 2, nq = t & 3;
        bf16x8 o0, o1;
        #pragma unroll
        for (int i = 0; i < 8; ++i) { o0[i] = T[nq * 16 + i][dl]; o1[i] = T[nq * 16 + 8 + i][dl]; }
        __bf16* dst = vt + ((size_t)((b * 16 + h) * 64 + dl)) * 1024 + nb * 64 + nq * 16;
        *(bf16x8*)dst = o0;
        *(bf16x8*)(dst + 8) = o1;
    }
}

// ---------------------------------------------------------------- flash attention v3
__global__ __launch_bounds__(256, 2)
void attn_kernel(const __bf16* __restrict__ qkv, const __bf16* __restrict__ vt,
                 __bf16* __restrict__ ao)
{
    __shared__ __bf16 Ks[2][64 * 64];
    __shared__ __bf16 Vs[2][64 * 64];
    __shared__ __bf16 Pl[4][16 * 64];
    const int tid = threadIdx.x, l = tid & 63, w = tid >> 6;
    const int fr = l & 15, fk = l >> 4;
    const int sw = (fr & 7) << 4;

    const int bi = blockIdx.x;
    const int L = (bi & 7) * 128 + (bi >> 3);
    const int qb = L & 3, h = (L >> 2) & 15, b = L >> 6;

    const __bf16* Kg = qkv + (size_t)b * 1024 * 3072 + 1024 + h * 64;
    const __bf16* Vg = vt + (size_t)((b * 16 + h) * 64) * 1024;
    const int srow = tid >> 3, scp = tid & 7;

#define STAGE(KT, BUF) do {                                                               \
    _Pragma("unroll")                                                                     \
    for (int i_ = 0; i_ < 2; ++i_) {                                                      \
        const int row_ = i_ * 32 + srow;                                                  \
        const int c_ = scp ^ (row_ & 7);                                                  \
        __builtin_amdgcn_global_load_lds(AS1(Kg + (size_t)((KT) * 64 + row_) * 3072 + c_ * 8), \
                                         AS3(&Ks[BUF][i_ * 2048 + tid * 8]), 16, 0, 0);   \
        __builtin_amdgcn_global_load_lds(AS1(Vg + (size_t)row_ * 1024 + (KT) * 64 + c_ * 8),   \
                                         AS3(&Vs[BUF][i_ * 2048 + tid * 8]), 16, 0, 0);   \
    } } while (0)

    STAGE(0, 0);

    const int qrow0 = b * 1024 + qb * 256 + w * 64;
    bf16x8 qf[4][2];
    #pragma unroll
    for (int qi = 0; qi < 4; ++qi)
        #pragma unroll
        for (int dc = 0; dc < 2; ++dc)
            qf[qi][dc] = *(const bf16x8*)&qkv[(size_t)(qrow0 + qi * 16 + fr) * 3072
                                              + h * 64 + dc * 32 + fk * 8];

    f32x4 oacc[4][4] = {};
    float m_r[4], ls[4];
    #pragma unroll
    for (int qi = 0; qi < 4; ++qi) { m_r[qi] = -1e30f; ls[qi] = 0.0f; }

    char* Pw = (char*)&Pl[w][0];
    __syncthreads();

    for (int kt = 0; kt < 16; ++kt) {
        const int cur = kt & 1;
        if (kt < 15) STAGE(kt + 1, cur ^ 1);

        bf16x8 kf[4][2], vf[4][2];
        #pragma unroll
        for (int n = 0; n < 4; ++n)
            #pragma unroll
            for (int dc = 0; dc < 2; ++dc)
                kf[n][dc] = *(const bf16x8*)&Ks[cur][(n * 16 + fr) * 64
                                                     + (((dc * 4 + fk) ^ (fr & 7)) * 8)];
        #pragma unroll
        for (int nd = 0; nd < 4; ++nd)
            #pragma unroll
            for (int kc = 0; kc < 2; ++kc)
                vf[nd][kc] = *(const bf16x8*)&Vs[cur][(nd * 16 + fr) * 64
                                                      + (((kc * 4 + fk) ^ (fr & 7)) * 8)];

        #pragma unroll
        for (int qi = 0; qi < 4; ++qi) {
            f32x4 sacc[4] = {};
            #pragma unroll
            for (int n = 0; n < 4; ++n)
                #pragma unroll
                for (int dc = 0; dc < 2; ++dc)
                    sacc[n] = __builtin_amdgcn_mfma_f32_16x16x32_bf16(kf[n][dc], qf[qi][dc],
                                                                      sacc[n], 0, 0, 0);

            float tm = -1e30f;
            #pragma unroll
            for (int n = 0; n < 4; ++n)
                #pragma unroll
                for (int r = 0; r < 4; ++r)
                    tm = fmaxf(tm, sacc[n][r]);
            tm = fmaxf(tm, __shfl_xor(tm, 16));
            tm = fmaxf(tm, __shfl_xor(tm, 32));
            const float mnew = fmaxf(m_r[qi], tm);
            const float resc = __expf(m_r[qi] - mnew);
            m_r[qi] = mnew;

            float psum = 0.0f;
            #pragma unroll
            for (int n = 0; n < 4; ++n) {
                bf16x4 pk;
                #pragma unroll
                for (int r = 0; r < 4; ++r) {
                    float p = __expf(sacc[n][r] - mnew);
                    psum += p;
                    pk[r] = (__bf16)p;
                }
                *(bf16x4*)(Pw + ((fr * 128 + n * 32 + fk * 8) ^ sw)) = pk;
            }
            psum += __shfl_xor(psum, 16);
            psum += __shfl_xor(psum, 32);
            ls[qi] = ls[qi] * resc + psum;

            float rb[4];
            #pragma unroll
            for (int r = 0; r < 4; ++r) rb[r] = __shfl(resc, (l & 48) + fk * 4 + r);
            #pragma unroll
            for (int nd = 0; nd < 4; ++nd)
                #pragma unroll
                for (int r = 0; r < 4; ++r) oacc[qi][nd][r] *= rb[r];

            bf16x8 pf[2];
            #pragma unroll
            for (int kc = 0; kc < 2; ++kc)
                pf[kc] = *(const bf16x8*)(Pw + ((fr * 128 + kc * 64 + fk * 16) ^ sw));
            #pragma unroll
            for (int nd = 0; nd < 4; ++nd)
                #pragma unroll
                for (int kc = 0; kc < 2; ++kc)
                    oacc[qi][nd] = __builtin_amdgcn_mfma_f32_16x16x32_bf16(pf[kc], vf[nd][kc],
                                                                           oacc[qi][nd], 0, 0, 0);
        }
        __syncthreads();
    }

    #pragma unroll
    for (int qi = 0; qi < 4; ++qi) {
        float lsb[4];
        #pragma unroll
        for (int r = 0; r < 4; ++r) lsb[r] = __shfl(ls[qi], (l & 48) + fk * 4 + r);
        #pragma unroll
        for (int nd = 0; nd < 4; ++nd)
            #pragma unroll
            for (int r = 0; r < 4; ++r)
                ao[(size_t)(qrow0 + qi * 16 + fk * 4 + r) * 1024 + h * 64 + nd * 16 + fr] =
                    (__bf16)(oacc[qi][nd][r] / lsb[r]);
    }
#undef STAGE
}

// ---------------------------------------------------------------- launch
extern "C" void kernel_launch(void* const* d_in, const int* in_sizes, int n_in,
                              void* d_out, int out_size, void* d_ws, size_t ws_size,
                              hipStream_t stream)
{
    const float* x      = (const float*)d_in[0];
    const float* qkv_w  = (const float*)d_in[1];
    const float* proj_w = (const float*)d_in[2];
    const float* proj_b = (const float*)d_in[3];
    const float* qnw    = (const float*)d_in[4];
    const float* knw    = (const float*)d_in[5];

    char* ws = (char*)d_ws;
    __bf16* xb    = (__bf16*)(ws);                                 // 32 MB (reused as vt later)
    __bf16* wqkv  = (__bf16*)(ws + 33554432);                      // 6 MB
    __bf16* wproj = (__bf16*)(ws + 33554432 + 6291456);            // 2 MB
    __bf16* qkv   = (__bf16*)(ws + 41943040);                      // 96 MB
    __bf16* ao    = (__bf16*)(ws + 41943040 + 100663296);          // 32 MB
    __bf16* vt    = xb;                                            // xb dead after QKV GEMM

    f2b_kernel<<<2048, 256, 0, stream>>>((const float4*)x,      (bf16x4*)xb,    16777216 / 4);
    f2b_kernel<<<2048, 256, 0, stream>>>((const float4*)qkv_w,  (bf16x4*)wqkv,  3145728 / 4);
    f2b_kernel<<<1024, 256, 0, stream>>>((const float4*)proj_w, (bf16x4*)wproj, 1048576 / 4);

    gemm256<0><<<768, 512, 0, stream>>>(xb, wqkv, nullptr, qnw, knw,
                                        nullptr, qkv, 16384, 3072, 1024, 12);
    vtrans_kernel<<<dim3(16, 16, 16), 256, 0, stream>>>(qkv, vt);
    attn_kernel<<<1024, 256, 0, stream>>>(qkv, vt, ao);
    gemm256<1><<<256, 512, 0, stream>>>(ao, wproj, proj_b, nullptr, nullptr,
                                        (float*)d_out, nullptr, 16384, 1024, 1024, 4);
}